// Round 6
// baseline (3038.165 us; speedup 1.0000x reference)
//
#include <hip/hip_runtime.h>

typedef unsigned int uint;

__device__ __forceinline__ float bfl(uint u){ return __uint_as_float(u << 16); }
__device__ __forceinline__ float bfh(uint u){ return __uint_as_float(u & 0xFFFF0000u); }
__device__ __forceinline__ uint f2bfbits(float f){
    uint b = __float_as_uint(f);
    return (b + 0x7FFFu + ((b >> 16) & 1u)) >> 16;
}
__device__ __forceinline__ uint packbf2(float a, float b){
    return f2bfbits(a) | (f2bfbits(b) << 16);
}
__device__ __forceinline__ int smap(int4 m, int s){
    return (s == 0) ? m.x : (s == 1) ? m.y : (s == 2) ? m.z : m.w;
}
__device__ __forceinline__ int2 ldnt(const int2* p){
    long long v = __builtin_nontemporal_load((const long long*)p);
    int2 r; r.x = (int)(v & 0xFFFFFFFFll); r.y = (int)(v >> 32); return r;
}

#define CH 6144
#define SBSHIFT 10
#define SBROWS 1024
#define PGRID 2048       // persistent spmm grid (co-resident: 8 blocks/CU x 256 CU)

// ---------------- dense part ----------------

#define BM 64
#define BK 32
// AB[N][256]: cols 0..127 = x@Wa, 128..255 = x@Wb. One pass, x read once.
__global__ __launch_bounds__(256) void gemm_kernel(const float* __restrict__ x,
                                                   const float* __restrict__ Wa,
                                                   const float* __restrict__ Wb,
                                                   float* __restrict__ AB, int N) {
    __shared__ float xsT[BK][BM + 4];
    __shared__ float wsm[BK][256];
    int t = threadIdx.x;
    int rowbase = blockIdx.x * BM;
    int tx = t & 15, ty = t >> 4;
    float acc[4][16];
    #pragma unroll
    for (int i = 0; i < 4; i++)
        #pragma unroll
        for (int j = 0; j < 16; j++) acc[i][j] = 0.f;

    for (int k0 = 0; k0 < 256; k0 += BK) {
        {
            int r = t & 63;
            int koff = (t >> 6) * 8;
            int gr = rowbase + r; if (gr >= N) gr = N - 1;
            const float* src = x + (size_t)gr * 256 + k0 + koff;
            float4 u0 = *(const float4*)(src);
            float4 u1 = *(const float4*)(src + 4);
            xsT[koff + 0][r] = u0.x; xsT[koff + 1][r] = u0.y;
            xsT[koff + 2][r] = u0.z; xsT[koff + 3][r] = u0.w;
            xsT[koff + 4][r] = u1.x; xsT[koff + 5][r] = u1.y;
            xsT[koff + 6][r] = u1.z; xsT[koff + 7][r] = u1.w;
        }
        {
            #pragma unroll
            for (int i = 0; i < 8; i++) {
                int f = t + i * 256;
                int rr = f >> 6, c4 = f & 63;
                const float* src = (c4 < 32) ? &Wa[(size_t)(k0 + rr) * 128 + c4 * 4]
                                             : &Wb[(size_t)(k0 + rr) * 128 + (c4 - 32) * 4];
                *(float4*)&wsm[rr][c4 * 4] = *(const float4*)src;
            }
        }
        __syncthreads();
        #pragma unroll
        for (int kk = 0; kk < BK; ++kk) {
            float4 a = *(const float4*)&xsT[kk][ty * 4];
            float av[4] = {a.x, a.y, a.z, a.w};
            float bv[16];
            #pragma unroll
            for (int q = 0; q < 4; q++)
                *(float4*)&bv[q * 4] = *(const float4*)&wsm[kk][q * 64 + tx * 4];
            #pragma unroll
            for (int i = 0; i < 4; i++)
                #pragma unroll
                for (int j = 0; j < 16; j++)
                    acc[i][j] = fmaf(av[i], bv[j], acc[i][j]);
        }
        __syncthreads();
    }
    #pragma unroll
    for (int i = 0; i < 4; i++) {
        int gr = rowbase + ty * 4 + i;
        if (gr < N) {
            #pragma unroll
            for (int q = 0; q < 4; q++) {
                float4 o = {acc[i][q*4], acc[i][q*4+1], acc[i][q*4+2], acc[i][q*4+3]};
                *(float4*)&AB[(size_t)gr * 256 + q * 64 + tx * 4] = o;
            }
        }
    }
}

// attention: Pb[n] packed bf16 [N][128]
__global__ __launch_bounds__(256) void attn_kernel(const float* __restrict__ AB,
        const float* __restrict__ w1, const float* __restrict__ b1,
        const float* __restrict__ w2, uint* __restrict__ Pb, int N) {
    __shared__ float w1s[128 * 32];
    __shared__ float b1s[32], w2s[32];
    __shared__ float aS[4][128], alS[4][128];
    int t = threadIdx.x;
    #pragma unroll
    for (int i = 0; i < 16; i++) w1s[t + i * 256] = w1[t + i * 256];
    if (t < 32) { b1s[t] = b1[t]; w2s[t] = w2[t]; }

    int w = t >> 6, lane = t & 63;
    int node = blockIdx.x * 4 + w;
    bool active = node < N;
    int nclamp = active ? node : (N - 1);
    float2 a = *(const float2*)(AB + (size_t)nclamp * 256 + lane * 2);
    float2 b = *(const float2*)(AB + (size_t)nclamp * 256 + 128 + lane * 2);
    float2 al;
    al.x = a.x + 0.5f * (a.x * a.x - a.x * b.x);
    al.y = a.y + 0.5f * (a.y * a.y - a.y * b.y);
    aS[w][lane * 2] = a.x;   aS[w][lane * 2 + 1] = a.y;
    alS[w][lane * 2] = al.x; alS[w][lane * 2 + 1] = al.y;
    __syncthreads();

    int j = lane & 31;
    const float* src = (lane < 32) ? aS[w] : alS[w];
    float acc = b1s[j];
    #pragma unroll 8
    for (int d = 0; d < 128; ++d) acc = fmaf(src[d], w1s[d * 32 + j], acc);
    float h = tanhf(acc);
    float prod = h * w2s[j];
    #pragma unroll
    for (int off = 1; off < 32; off <<= 1) prod += __shfl_xor(prod, off);
    float eo = __shfl_xor(prod, 32);
    float e0 = (lane < 32) ? prod : eo;
    float e1 = (lane < 32) ? eo : prod;
    float m = fmaxf(e0, e1);
    float p0 = expf(e0 - m), p1 = expf(e1 - m);
    float inv = 1.0f / (p0 + p1);
    float at0 = p0 * inv, at1 = p1 * inv;
    if (active) {
        float px = at0 * a.x + at1 * al.x;
        float py = at0 * a.y + at1 * al.y;
        Pb[(size_t)node * 64 + lane] = packbf2(px, py);
    }
}

// ---------------- CSR build: chunk-local binning, zero global atomics ----------------

__global__ __launch_bounds__(256) void fill_chunk(const int* __restrict__ rows,
        const int* __restrict__ cols, const float* __restrict__ vals, int4 map,
        int2* __restrict__ stage, int* __restrict__ offTab, int* __restrict__ lenTab,
        int NSB, int nchunks, int E) {
    __shared__ int2 sbuf[CH];
    __shared__ int hist[128];
    __shared__ int wtot;
    int c = blockIdx.x, s = blockIdx.y, t = threadIdx.x;
    size_t sb = (size_t)smap(map, s) * E;
    int e0 = c * CH;
    int e1 = e0 + CH; if (e1 > E) e1 = E;
    int csz = e1 - e0;
    if (t < 128) hist[t] = 0;
    __syncthreads();
    for (int e = e0 + t; e < e1; e += 256)
        atomicAdd(&hist[(uint)rows[sb + e] >> SBSHIFT], 1);
    __syncthreads();
    int v = 0, incl = 0;
    if (t < 128) {
        v = hist[t]; incl = v;
        #pragma unroll
        for (int off = 1; off < 64; off <<= 1) {
            int y = __shfl_up(incl, off);
            if ((t & 63) >= off) incl += y;
        }
        if (t == 63) wtot = incl;
    }
    __syncthreads();
    if (t < 128) {
        int excl = incl - v + ((t >= 64) ? wtot : 0);
        hist[t] = excl;
        if (t < NSB) {
            size_t tb = ((size_t)s * nchunks + c) * NSB + t;
            offTab[tb] = excl;
            lenTab[tb] = v;
        }
    }
    __syncthreads();
    for (int e = e0 + t; e < e1; e += 256) {
        int r = rows[sb + e];
        int pos = atomicAdd(&hist[(uint)r >> SBSHIFT], 1);
        uint cw = (uint)cols[sb + e] | ((uint)(r & (SBROWS - 1)) << 20);
        sbuf[pos] = make_int2((int)cw, __float_as_int(vals[sb + e]));
    }
    __syncthreads();
    int2* dst = stage + (size_t)s * E + e0;
    for (int i = t; i < csz; i += 256)
        __builtin_nontemporal_store(*(const long long*)&sbuf[i], (long long*)&dst[i]);
}

__global__ __launch_bounds__(256) void bucket_scan(const int* __restrict__ lenTab,
        int* __restrict__ bbase, int NSB, int nchunks) {
    __shared__ int tot[128];
    __shared__ int wtot;
    int s = blockIdx.x, t = threadIdx.x;
    if (t < 128) tot[t] = 0;
    __syncthreads();
    if (t < NSB) {
        int acc = 0;
        for (int c = 0; c < nchunks; ++c)
            acc += lenTab[((size_t)s * nchunks + c) * NSB + t];
        tot[t] = acc;
    }
    __syncthreads();
    int v = 0, incl = 0;
    if (t < 128) {
        v = tot[t]; incl = v;
        #pragma unroll
        for (int off = 1; off < 64; off <<= 1) {
            int y = __shfl_up(incl, off);
            if ((t & 63) >= off) incl += y;
        }
        if (t == 63) wtot = incl;
    }
    __syncthreads();
    if (t < NSB) bbase[s * NSB + t] = incl - v + ((t >= 64) ? wtot : 0);
}

__device__ __forceinline__ void block_scan1024(int* a, int t, int* wsum) {
    int lane = t & 63, wid = t >> 6;
    int c0 = a[t * 4], c1 = a[t * 4 + 1], c2 = a[t * 4 + 2], c3 = a[t * 4 + 3];
    int tsum = c0 + c1 + c2 + c3, incl = tsum;
    #pragma unroll
    for (int off = 1; off < 64; off <<= 1) {
        int y = __shfl_up(incl, off);
        if (lane >= off) incl += y;
    }
    if (lane == 63) wsum[wid] = incl;
    __syncthreads();
    int wb = 0;
    #pragma unroll
    for (int w = 0; w < 4; w++) if (w < wid) wb += wsum[w];
    int excl = wb + incl - tsum;
    a[t * 4] = excl; a[t * 4 + 1] = excl + c0;
    a[t * 4 + 2] = excl + c0 + c1; a[t * 4 + 3] = excl + c0 + c1 + c2;
    __syncthreads();
}

__global__ __launch_bounds__(256) void fill_bucket(const int2* __restrict__ stage,
        const int* __restrict__ offTab, const int* __restrict__ lenTab,
        const int* __restrict__ bbase, int* __restrict__ rp, int2* __restrict__ pk,
        int NSB, int nchunks, int N, int E) {
    __shared__ int lh[SBROWS];
    __shared__ int wsum[4];
    int b = blockIdx.x, s = blockIdx.y, t = threadIdx.x;
    int rowbase = b << SBSHIFT;
    int nrows = N - rowbase; if (nrows > SBROWS) nrows = SBROWS;
    #pragma unroll
    for (int k = 0; k < 4; k++) lh[t + k * 256] = 0;
    __syncthreads();
    size_t sb = (size_t)s * E;
    int wid = t >> 6, lane = t & 63;
    for (int c = wid; c < nchunks; c += 4) {
        size_t tb = ((size_t)s * nchunks + c) * NSB + b;
        int off = offTab[tb], len = lenTab[tb];
        const int2* seg = stage + sb + (size_t)c * CH + off;
        for (int i = lane; i < len; i += 64)
            atomicAdd(&lh[((uint)ldnt(&seg[i]).x) >> 20], 1);
    }
    __syncthreads();
    block_scan1024(lh, t, wsum);
    int bb = bbase[s * NSB + b];
    #pragma unroll
    for (int k = 0; k < 4; k++) {
        int i = t * 4 + k;
        int curv = lh[i] + bb;
        lh[i] = curv;
        if (i < nrows) rp[(size_t)s * (N + 1) + rowbase + i] = curv;
    }
    if (b == 0 && t == 0) rp[(size_t)s * (N + 1) + N] = E;
    __syncthreads();
    for (int c = wid; c < nchunks; c += 4) {
        size_t tb = ((size_t)s * nchunks + c) * NSB + b;
        int off = offTab[tb], len = lenTab[tb];
        const int2* seg = stage + sb + (size_t)c * CH + off;
        for (int i = lane; i < len; i += 64) {
            int2 u = ldnt(&seg[i]);
            int lr = ((uint)u.x) >> 20;
            int pos = atomicAdd(&lh[lr], 1);
            pk[sb + pos] = make_int2(u.x & 0xFFFFF, u.y);
        }
    }
}

// per-row col-sort (<=64 edges): bitonic across the wave. Permutation only.
__global__ __launch_bounds__(256) void sort_rows(const int* __restrict__ rp,
        int2* __restrict__ pk, int N, int E) {
    int w = threadIdx.x >> 6, lane = threadIdx.x & 63;
    int row = blockIdx.x * 4 + w;
    int s = blockIdx.y;
    if (row >= N) return;
    const int* rps = rp + (size_t)s * (N + 1);
    int2* pks = pk + (size_t)s * E;
    int beg = rps[row], deg = rps[row + 1] - beg;
    if (deg < 2 || deg > 64) return;
    int key = 0x7FFFFFFF, val = 0;
    if (lane < deg) { int2 u = pks[beg + lane]; key = u.x; val = u.y; }
    #pragma unroll
    for (int k = 2; k <= 64; k <<= 1) {
        #pragma unroll
        for (int j = k >> 1; j > 0; j >>= 1) {
            int okey = __shfl_xor(key, j);
            int oval = __shfl_xor(val, j);
            bool up = ((lane & k) == 0);
            bool lower = ((lane & j) == 0);
            bool keepmin = (lower == up);
            bool take = keepmin ? (okey < key) : (okey > key);
            if (take) { key = okey; val = oval; }
        }
    }
    if (lane < deg) pks[beg + lane] = make_int2(key, val);
}

// ---------------- fused SpMM kernels (persistent, sorted-walk, MLP=4) ----------------

__device__ __forceinline__ void row_gather_sum(const int2* __restrict__ pk,
        int e, int end, const uint* __restrict__ Xb, int lane,
        float& ax, float& ay) {
    for (; e + 4 <= end; e += 4) {
        int2 c0 = ldnt(&pk[e]);     int2 c1 = ldnt(&pk[e + 1]);
        int2 c2 = ldnt(&pk[e + 2]); int2 c3 = ldnt(&pk[e + 3]);
        uint u0 = Xb[(c0.x << 6) + lane]; uint u1 = Xb[(c1.x << 6) + lane];
        uint u2 = Xb[(c2.x << 6) + lane]; uint u3 = Xb[(c3.x << 6) + lane];
        float v0 = __int_as_float(c0.y), v1 = __int_as_float(c1.y);
        float v2 = __int_as_float(c2.y), v3 = __int_as_float(c3.y);
        ax = fmaf(v0, bfl(u0), ax); ay = fmaf(v0, bfh(u0), ay);
        ax = fmaf(v1, bfl(u1), ax); ay = fmaf(v1, bfh(u1), ay);
        ax = fmaf(v2, bfl(u2), ax); ay = fmaf(v2, bfh(u2), ay);
        ax = fmaf(v3, bfl(u3), ax); ay = fmaf(v3, bfh(u3), ay);
    }
    for (; e < end; ++e) {
        int2 c0 = ldnt(&pk[e]);
        uint u0 = Xb[(c0.x << 6) + lane];
        float v0 = __int_as_float(c0.y);
        ax = fmaf(v0, bfl(u0), ax); ay = fmaf(v0, bfh(u0), ay);
    }
}

__device__ __forceinline__ void row_gather_bp(const int2* __restrict__ pk,
        int e, int end, const uint* __restrict__ Xb, int lane,
        float& sx, float& sy, float& qx, float& qy) {
    for (; e + 4 <= end; e += 4) {
        int2 c0 = ldnt(&pk[e]);     int2 c1 = ldnt(&pk[e + 1]);
        int2 c2 = ldnt(&pk[e + 2]); int2 c3 = ldnt(&pk[e + 3]);
        uint u0 = Xb[(c0.x << 6) + lane]; uint u1 = Xb[(c1.x << 6) + lane];
        uint u2 = Xb[(c2.x << 6) + lane]; uint u3 = Xb[(c3.x << 6) + lane];
        float v0 = __int_as_float(c0.y), v1 = __int_as_float(c1.y);
        float v2 = __int_as_float(c2.y), v3 = __int_as_float(c3.y);
        float x0 = bfl(u0), y0 = bfh(u0), x1 = bfl(u1), y1 = bfh(u1);
        float x2 = bfl(u2), y2 = bfh(u2), x3 = bfl(u3), y3 = bfh(u3);
        sx = fmaf(v0, x0, sx); sy = fmaf(v0, y0, sy);
        qx = fmaf(v0 * x0, x0, qx); qy = fmaf(v0 * y0, y0, qy);
        sx = fmaf(v1, x1, sx); sy = fmaf(v1, y1, sy);
        qx = fmaf(v1 * x1, x1, qx); qy = fmaf(v1 * y1, y1, qy);
        sx = fmaf(v2, x2, sx); sy = fmaf(v2, y2, sy);
        qx = fmaf(v2 * x2, x2, qx); qy = fmaf(v2 * y2, y2, qy);
        sx = fmaf(v3, x3, sx); sy = fmaf(v3, y3, sy);
        qx = fmaf(v3 * x3, x3, qx); qy = fmaf(v3 * y3, y3, qy);
    }
    for (; e < end; ++e) {
        int2 c0 = ldnt(&pk[e]);
        uint u0 = Xb[(c0.x << 6) + lane];
        float v0 = __int_as_float(c0.y);
        float x0 = bfl(u0), y0 = bfh(u0);
        sx = fmaf(v0, x0, sx); sy = fmaf(v0, y0, sy);
        qx = fmaf(v0 * x0, x0, qx); qy = fmaf(v0 * y0, y0, qy);
    }
}

__global__ __launch_bounds__(256) void spmm_bp2(const int* __restrict__ rpA,
        const int2* __restrict__ pkA, const int* __restrict__ rpB,
        const int2* __restrict__ pkB, const uint* __restrict__ Xb,
        uint* __restrict__ outb, int N) {
    int w = threadIdx.x >> 6, lane = threadIdx.x & 63;
    int stride = gridDim.x * 4;
    for (int row = blockIdx.x * 4 + w; row < N; row += stride) {
        float sax = 0.f, say = 0.f, qax = 0.f, qay = 0.f;
        float sbx = 0.f, sby = 0.f, qbx = 0.f, qby = 0.f;
        row_gather_bp(pkA, rpA[row], rpA[row + 1], Xb, lane, sax, say, qax, qay);
        row_gather_bp(pkB, rpB[row], rpB[row + 1], Xb, lane, sbx, sby, qbx, qby);
        float tx = 0.5f * ((sax * sax - qax) - (sbx * sbx - qbx));
        float ty = 0.5f * ((say * say - qay) - (sby * sby - qby));
        outb[((size_t)row << 6) + lane] = packbf2(tx, ty);
    }
}

__global__ __launch_bounds__(256) void spmm_out(const int* __restrict__ rp0,
        const int2* __restrict__ pk0, const int* __restrict__ rp5,
        const int2* __restrict__ pk5, const int* __restrict__ rp6,
        const int2* __restrict__ pk6, const uint* __restrict__ Pb,
        const uint* __restrict__ t1b, const uint* __restrict__ t2b,
        float* __restrict__ out, int N) {
    int w = threadIdx.x >> 6, lane = threadIdx.x & 63;
    int stride = gridDim.x * 4;
    for (int row = blockIdx.x * 4 + w; row < N; row += stride) {
        float a0x = 0.f, a0y = 0.f, a5x = 0.f, a5y = 0.f, a6x = 0.f, a6y = 0.f;
        row_gather_sum(pk0, rp0[row], rp0[row + 1], Pb,  lane, a0x, a0y);
        row_gather_sum(pk5, rp5[row], rp5[row + 1], t1b, lane, a5x, a5y);
        row_gather_sum(pk6, rp6[row], rp6[row + 1], t2b, lane, a6x, a6y);
        float rx = fmaxf(0.5f * a0x + 0.25f * a5x + 0.25f * a6x, 0.f);
        float ry = fmaxf(0.5f * a0y + 0.25f * a5y + 0.25f * a6y, 0.f);
        *(float2*)(out + ((size_t)row << 7) + (lane << 1)) = make_float2(rx, ry);
    }
}

// ---------------- launch ----------------

extern "C" void kernel_launch(void* const* d_in, const int* in_sizes, int n_in,
                              void* d_out, int out_size, void* d_ws, size_t ws_size,
                              hipStream_t stream) {
    (void)n_in; (void)out_size; (void)ws_size;
    const float* x   = (const float*)d_in[0];
    const float* Wa  = (const float*)d_in[1];
    const float* Wb  = (const float*)d_in[2];
    const float* w1  = (const float*)d_in[4];
    const float* b1  = (const float*)d_in[5];
    const float* w2  = (const float*)d_in[6];
    const int* rows  = (const int*)d_in[7];
    const int* cols  = (const int*)d_in[8];
    const float* vals = (const float*)d_in[9];
    float* out = (float*)d_out;

    const int N = in_sizes[0] / 256;
    const int E = in_sizes[7] / 7;
    const int NSB = (N + SBROWS - 1) >> SBSHIFT;
    const int nchunks = (E + CH - 1) / CH;

    uint* Pb  = (uint*)d_ws;
    uint* t1b = Pb + (size_t)N * 64;
    uint* t2b = t1b + (size_t)N * 64;
    int2* pk  = (int2*)(t2b + (size_t)N * 64);
    size_t regionFloats = (size_t)N * 256;
    if ((size_t)8 * E > regionFloats) regionFloats = (size_t)8 * E;
    int2* stage = pk + (size_t)4 * E;
    float* AB   = (float*)stage;
    int* rp     = (int*)((float*)stage + regionFloats);
    int* offTab = rp + 4 * (size_t)(N + 1);
    int* lenTab = offTab + (size_t)4 * nchunks * NSB;
    int* bbase  = lenTab + (size_t)4 * nchunks * NSB;

    dim3 b256(256);
    int sgrid = (N + 3) / 4;
    int pgrid = PGRID; if (pgrid > sgrid) pgrid = sgrid;

    gemm_kernel<<<(N + BM - 1) / BM, b256, 0, stream>>>(x, Wa, Wb, AB, N);
    attn_kernel<<<sgrid, b256, 0, stream>>>(AB, w1, b1, w2, Pb, N);

    auto build = [&](int4 map, int nsup) {
        fill_chunk<<<dim3(nchunks, nsup), b256, 0, stream>>>(rows, cols, vals, map,
                                                             stage, offTab, lenTab, NSB, nchunks, E);
        bucket_scan<<<nsup, b256, 0, stream>>>(lenTab, bbase, NSB, nchunks);
        fill_bucket<<<dim3(NSB, nsup), b256, 0, stream>>>(stage, offTab, lenTab, bbase,
                                                          rp, pk, NSB, nchunks, N, E);
        sort_rows<<<dim3(sgrid, nsup), b256, 0, stream>>>(rp, pk, N, E);
    };

    const int NP1 = N + 1;

    // group A: slots {1,3,2,4}
    build(make_int4(1, 3, 2, 4), 4);
    spmm_bp2<<<pgrid, b256, 0, stream>>>(rp + 0 * NP1, pk + 0 * (size_t)E,
                                         rp + 1 * NP1, pk + 1 * (size_t)E, Pb, t1b, N);
    spmm_bp2<<<pgrid, b256, 0, stream>>>(rp + 2 * NP1, pk + 2 * (size_t)E,
                                         rp + 3 * NP1, pk + 3 * (size_t)E, Pb, t2b, N);

    // group B: slots {0,5,6}
    build(make_int4(0, 5, 6, 6), 3);
    spmm_out<<<pgrid, b256, 0, stream>>>(rp + 0 * NP1, pk + 0 * (size_t)E,
                                         rp + 1 * NP1, pk + 1 * (size_t)E,
                                         rp + 2 * NP1, pk + 2 * (size_t)E,
                                         Pb, t1b, t2b, out, N);
}

// Round 7
// 2399.223 us; speedup vs baseline: 1.2663x; 1.2663x over previous
//
#include <hip/hip_runtime.h>

typedef unsigned int uint;

__device__ __forceinline__ float bfl(uint u){ return __uint_as_float(u << 16); }
__device__ __forceinline__ float bfh(uint u){ return __uint_as_float(u & 0xFFFF0000u); }
__device__ __forceinline__ uint f2bfbits(float f){
    uint b = __float_as_uint(f);
    return (b + 0x7FFFu + ((b >> 16) & 1u)) >> 16;
}
__device__ __forceinline__ uint packbf2(float a, float b){
    return f2bfbits(a) | (f2bfbits(b) << 16);
}
__device__ __forceinline__ int smap(int4 m, int s){
    return (s == 0) ? m.x : (s == 1) ? m.y : (s == 2) ? m.z : m.w;
}
__device__ __forceinline__ int2 ldnt(const int2* p){
    long long v = __builtin_nontemporal_load((const long long*)p);
    int2 r; r.x = (int)(v & 0xFFFFFFFFll); r.y = (int)(v >> 32); return r;
}

#define CH 6144
#define SBSHIFT 10
#define SBROWS 1024
#define MAXCH 544        // >= nchunks = ceil(E/CH); E=3.2M -> 521
#define PGRID 2048

// ---------------- dense part ----------------

#define BM 64
#define BK 32
__global__ __launch_bounds__(256) void gemm_kernel(const float* __restrict__ x,
                                                   const float* __restrict__ Wa,
                                                   const float* __restrict__ Wb,
                                                   float* __restrict__ AB, int N) {
    __shared__ float xsT[BK][BM + 4];
    __shared__ float wsm[BK][256];
    int t = threadIdx.x;
    int rowbase = blockIdx.x * BM;
    int tx = t & 15, ty = t >> 4;
    float acc[4][16];
    #pragma unroll
    for (int i = 0; i < 4; i++)
        #pragma unroll
        for (int j = 0; j < 16; j++) acc[i][j] = 0.f;

    for (int k0 = 0; k0 < 256; k0 += BK) {
        {
            int r = t & 63;
            int koff = (t >> 6) * 8;
            int gr = rowbase + r; if (gr >= N) gr = N - 1;
            const float* src = x + (size_t)gr * 256 + k0 + koff;
            float4 u0 = *(const float4*)(src);
            float4 u1 = *(const float4*)(src + 4);
            xsT[koff + 0][r] = u0.x; xsT[koff + 1][r] = u0.y;
            xsT[koff + 2][r] = u0.z; xsT[koff + 3][r] = u0.w;
            xsT[koff + 4][r] = u1.x; xsT[koff + 5][r] = u1.y;
            xsT[koff + 6][r] = u1.z; xsT[koff + 7][r] = u1.w;
        }
        {
            #pragma unroll
            for (int i = 0; i < 8; i++) {
                int f = t + i * 256;
                int rr = f >> 6, c4 = f & 63;
                const float* src = (c4 < 32) ? &Wa[(size_t)(k0 + rr) * 128 + c4 * 4]
                                             : &Wb[(size_t)(k0 + rr) * 128 + (c4 - 32) * 4];
                *(float4*)&wsm[rr][c4 * 4] = *(const float4*)src;
            }
        }
        __syncthreads();
        #pragma unroll
        for (int kk = 0; kk < BK; ++kk) {
            float4 a = *(const float4*)&xsT[kk][ty * 4];
            float av[4] = {a.x, a.y, a.z, a.w};
            float bv[16];
            #pragma unroll
            for (int q = 0; q < 4; q++)
                *(float4*)&bv[q * 4] = *(const float4*)&wsm[kk][q * 64 + tx * 4];
            #pragma unroll
            for (int i = 0; i < 4; i++)
                #pragma unroll
                for (int j = 0; j < 16; j++)
                    acc[i][j] = fmaf(av[i], bv[j], acc[i][j]);
        }
        __syncthreads();
    }
    #pragma unroll
    for (int i = 0; i < 4; i++) {
        int gr = rowbase + ty * 4 + i;
        if (gr < N) {
            #pragma unroll
            for (int q = 0; q < 4; q++) {
                float4 o = {acc[i][q*4], acc[i][q*4+1], acc[i][q*4+2], acc[i][q*4+3]};
                *(float4*)&AB[(size_t)gr * 256 + q * 64 + tx * 4] = o;
            }
        }
    }
}

// attention: Pb[n] packed bf16 [N][128]
__global__ __launch_bounds__(256) void attn_kernel(const float* __restrict__ AB,
        const float* __restrict__ w1, const float* __restrict__ b1,
        const float* __restrict__ w2, uint* __restrict__ Pb, int N) {
    __shared__ float w1s[128 * 32];
    __shared__ float b1s[32], w2s[32];
    __shared__ float aS[4][128], alS[4][128];
    int t = threadIdx.x;
    #pragma unroll
    for (int i = 0; i < 16; i++) w1s[t + i * 256] = w1[t + i * 256];
    if (t < 32) { b1s[t] = b1[t]; w2s[t] = w2[t]; }

    int w = t >> 6, lane = t & 63;
    int node = blockIdx.x * 4 + w;
    bool active = node < N;
    int nclamp = active ? node : (N - 1);
    float2 a = *(const float2*)(AB + (size_t)nclamp * 256 + lane * 2);
    float2 b = *(const float2*)(AB + (size_t)nclamp * 256 + 128 + lane * 2);
    float2 al;
    al.x = a.x + 0.5f * (a.x * a.x - a.x * b.x);
    al.y = a.y + 0.5f * (a.y * a.y - a.y * b.y);
    aS[w][lane * 2] = a.x;   aS[w][lane * 2 + 1] = a.y;
    alS[w][lane * 2] = al.x; alS[w][lane * 2 + 1] = al.y;
    __syncthreads();

    int j = lane & 31;
    const float* src = (lane < 32) ? aS[w] : alS[w];
    float acc = b1s[j];
    #pragma unroll 8
    for (int d = 0; d < 128; ++d) acc = fmaf(src[d], w1s[d * 32 + j], acc);
    float h = tanhf(acc);
    float prod = h * w2s[j];
    #pragma unroll
    for (int off = 1; off < 32; off <<= 1) prod += __shfl_xor(prod, off);
    float eo = __shfl_xor(prod, 32);
    float e0 = (lane < 32) ? prod : eo;
    float e1 = (lane < 32) ? eo : prod;
    float m = fmaxf(e0, e1);
    float p0 = expf(e0 - m), p1 = expf(e1 - m);
    float inv = 1.0f / (p0 + p1);
    float at0 = p0 * inv, at1 = p1 * inv;
    if (active) {
        float px = at0 * a.x + at1 * al.x;
        float py = at0 * a.y + at1 * al.y;
        Pb[(size_t)node * 64 + lane] = packbf2(px, py);
    }
}

// ---------------- CSR build ----------------

// pass A: chunk-local binning into 1024-row super-buckets; linear stage write.
// tables laid out [s][bucket][chunk] for pass-B contiguity.
__global__ __launch_bounds__(256) void fill_chunk(const int* __restrict__ rows,
        const int* __restrict__ cols, const float* __restrict__ vals, int4 map,
        int2* __restrict__ stage, int* __restrict__ offTab, int* __restrict__ lenTab,
        int NSB, int nchunks, int E) {
    __shared__ int2 sbuf[CH];
    __shared__ int hist[128];
    __shared__ int wtot;
    int c = blockIdx.x, s = blockIdx.y, t = threadIdx.x;
    size_t sb = (size_t)smap(map, s) * E;
    int e0 = c * CH;
    int e1 = e0 + CH; if (e1 > E) e1 = E;
    int csz = e1 - e0;
    if (t < 128) hist[t] = 0;
    __syncthreads();
    for (int e = e0 + t; e < e1; e += 256)
        atomicAdd(&hist[(uint)rows[sb + e] >> SBSHIFT], 1);
    __syncthreads();
    int v = 0, incl = 0;
    if (t < 128) {
        v = hist[t]; incl = v;
        #pragma unroll
        for (int off = 1; off < 64; off <<= 1) {
            int y = __shfl_up(incl, off);
            if ((t & 63) >= off) incl += y;
        }
        if (t == 63) wtot = incl;
    }
    __syncthreads();
    if (t < 128) {
        int excl = incl - v + ((t >= 64) ? wtot : 0);
        hist[t] = excl;
        if (t < NSB) {
            size_t tb = ((size_t)s * NSB + t) * nchunks + c;
            offTab[tb] = excl;
            lenTab[tb] = v;
        }
    }
    __syncthreads();
    for (int e = e0 + t; e < e1; e += 256) {
        int r = rows[sb + e];
        int pos = atomicAdd(&hist[(uint)r >> SBSHIFT], 1);
        uint cw = (uint)cols[sb + e] | ((uint)(r & (SBROWS - 1)) << 20);
        sbuf[pos] = make_int2((int)cw, __float_as_int(vals[sb + e]));
    }
    __syncthreads();
    int2* dst = stage + (size_t)s * E + e0;
    for (int i = t; i < csz; i += 256)
        __builtin_nontemporal_store(*(const long long*)&sbuf[i], (long long*)&dst[i]);
}

__global__ __launch_bounds__(256) void bucket_scan(const int* __restrict__ lenTab,
        int* __restrict__ bbase, int NSB, int nchunks) {
    __shared__ int tot[128];
    __shared__ int wtot;
    int s = blockIdx.x, t = threadIdx.x;
    if (t < 128) tot[t] = 0;
    __syncthreads();
    if (t < NSB) {
        const int* lt = lenTab + ((size_t)s * NSB + t) * nchunks;
        int acc = 0;
        for (int c = 0; c < nchunks; ++c) acc += lt[c];
        tot[t] = acc;
    }
    __syncthreads();
    int v = 0, incl = 0;
    if (t < 128) {
        v = tot[t]; incl = v;
        #pragma unroll
        for (int off = 1; off < 64; off <<= 1) {
            int y = __shfl_up(incl, off);
            if ((t & 63) >= off) incl += y;
        }
        if (t == 63) wtot = incl;
    }
    __syncthreads();
    if (t < NSB) bbase[s * NSB + t] = incl - v + ((t >= 64) ? wtot : 0);
}

// pass B: 1024 threads per (bucket,support). Tables staged in LDS; three phases:
// (1) row histogram, (2) scan+rp+placement, (3) per-row col-sort in the hot pk window.
__global__ __launch_bounds__(1024) void fill_bucket(const int2* __restrict__ stage,
        const int* __restrict__ offTab, const int* __restrict__ lenTab,
        const int* __restrict__ bbase, int* __restrict__ rp, int2* __restrict__ pk,
        int NSB, int nchunks, int N, int E) {
    __shared__ int lh[SBROWS];
    __shared__ int soff[MAXCH];
    __shared__ int slen[MAXCH];
    __shared__ int wsum[16];
    int b = blockIdx.x, s = blockIdx.y, t = threadIdx.x;
    int rowbase = b << SBSHIFT;
    int nrows = N - rowbase; if (nrows > SBROWS) nrows = SBROWS;
    int wid = t >> 6, lane = t & 63;

    lh[t] = 0;
    for (int i = t; i < nchunks; i += 1024) {
        size_t tb = ((size_t)s * NSB + b) * nchunks + i;
        soff[i] = offTab[tb];
        slen[i] = lenTab[tb];
    }
    __syncthreads();

    size_t sb = (size_t)s * E;
    // phase 1: histogram of local rows
    for (int c = wid; c < nchunks; c += 16) {
        int off = soff[c], len = slen[c];
        const int2* seg = stage + sb + (size_t)c * CH + off;
        for (int i = lane; i < len; i += 64)
            atomicAdd(&lh[((uint)seg[i].x) >> 20], 1);
    }
    __syncthreads();

    // phase 2a: block exclusive scan of lh (1024 elems, 1 per thread), += bucket base
    int bb = bbase[s * NSB + b];
    {
        int v = lh[t], incl = v;
        #pragma unroll
        for (int off = 1; off < 64; off <<= 1) {
            int y = __shfl_up(incl, off);
            if (lane >= off) incl += y;
        }
        if (lane == 63) wsum[wid] = incl;
        __syncthreads();
        int wb = 0;
        #pragma unroll
        for (int w = 0; w < 16; w++) if (w < wid) wb += wsum[w];
        lh[t] = bb + wb + incl - v;
    }
    __syncthreads();
    if (t < nrows) rp[(size_t)s * (N + 1) + rowbase + t] = lh[t];
    if (b == 0 && t == 0) rp[(size_t)s * (N + 1) + N] = E;
    __syncthreads();

    // phase 2b: placement
    for (int c = wid; c < nchunks; c += 16) {
        int off = soff[c], len = slen[c];
        const int2* seg = stage + sb + (size_t)c * CH + off;
        for (int i = lane; i < len; i += 64) {
            int2 u = seg[i];
            int lr = ((uint)u.x) >> 20;
            int pos = atomicAdd(&lh[lr], 1);
            pk[sb + pos] = make_int2(u.x & 0xFFFFF, u.y);
        }
    }
    __syncthreads();

    // phase 3: per-row bitonic col-sort (wave per row) while pk window is L2-hot.
    // lh[r] now = end of row r; beg = lh[r-1] (or bb for r==0).
    int2* pks = pk + sb;
    for (int r = wid; r < nrows; r += 16) {
        int beg = (r == 0) ? bb : lh[r - 1];
        int end = lh[r];
        int deg = end - beg;
        if (deg < 2 || deg > 64) continue;   // deg>64: leave unsorted (still correct)
        int key = 0x7FFFFFFF, val = 0;
        if (lane < deg) { int2 u = pks[beg + lane]; key = u.x; val = u.y; }
        #pragma unroll
        for (int k = 2; k <= 64; k <<= 1) {
            #pragma unroll
            for (int j = k >> 1; j > 0; j >>= 1) {
                int okey = __shfl_xor(key, j);
                int oval = __shfl_xor(val, j);
                bool up = ((lane & k) == 0);
                bool lower = ((lane & j) == 0);
                bool keepmin = (lower == up);
                bool take = keepmin ? (okey < key) : (okey > key);
                if (take) { key = okey; val = oval; }
            }
        }
        if (lane < deg) pks[beg + lane] = make_int2(key, val);
    }
}

// ---------------- fused SpMM kernels (persistent, sorted-walk, MLP=4) ----------------

__device__ __forceinline__ void row_gather_sum(const int2* __restrict__ pk,
        int e, int end, const uint* __restrict__ Xb, int lane,
        float& ax, float& ay) {
    for (; e + 4 <= end; e += 4) {
        int2 c0 = ldnt(&pk[e]);     int2 c1 = ldnt(&pk[e + 1]);
        int2 c2 = ldnt(&pk[e + 2]); int2 c3 = ldnt(&pk[e + 3]);
        uint u0 = Xb[(c0.x << 6) + lane]; uint u1 = Xb[(c1.x << 6) + lane];
        uint u2 = Xb[(c2.x << 6) + lane]; uint u3 = Xb[(c3.x << 6) + lane];
        float v0 = __int_as_float(c0.y), v1 = __int_as_float(c1.y);
        float v2 = __int_as_float(c2.y), v3 = __int_as_float(c3.y);
        ax = fmaf(v0, bfl(u0), ax); ay = fmaf(v0, bfh(u0), ay);
        ax = fmaf(v1, bfl(u1), ax); ay = fmaf(v1, bfh(u1), ay);
        ax = fmaf(v2, bfl(u2), ax); ay = fmaf(v2, bfh(u2), ay);
        ax = fmaf(v3, bfl(u3), ax); ay = fmaf(v3, bfh(u3), ay);
    }
    for (; e < end; ++e) {
        int2 c0 = ldnt(&pk[e]);
        uint u0 = Xb[(c0.x << 6) + lane];
        float v0 = __int_as_float(c0.y);
        ax = fmaf(v0, bfl(u0), ax); ay = fmaf(v0, bfh(u0), ay);
    }
}

__device__ __forceinline__ void row_gather_bp(const int2* __restrict__ pk,
        int e, int end, const uint* __restrict__ Xb, int lane,
        float& sx, float& sy, float& qx, float& qy) {
    for (; e + 4 <= end; e += 4) {
        int2 c0 = ldnt(&pk[e]);     int2 c1 = ldnt(&pk[e + 1]);
        int2 c2 = ldnt(&pk[e + 2]); int2 c3 = ldnt(&pk[e + 3]);
        uint u0 = Xb[(c0.x << 6) + lane]; uint u1 = Xb[(c1.x << 6) + lane];
        uint u2 = Xb[(c2.x << 6) + lane]; uint u3 = Xb[(c3.x << 6) + lane];
        float v0 = __int_as_float(c0.y), v1 = __int_as_float(c1.y);
        float v2 = __int_as_float(c2.y), v3 = __int_as_float(c3.y);
        float x0 = bfl(u0), y0 = bfh(u0), x1 = bfl(u1), y1 = bfh(u1);
        float x2 = bfl(u2), y2 = bfh(u2), x3 = bfl(u3), y3 = bfh(u3);
        sx = fmaf(v0, x0, sx); sy = fmaf(v0, y0, sy);
        qx = fmaf(v0 * x0, x0, qx); qy = fmaf(v0 * y0, y0, qy);
        sx = fmaf(v1, x1, sx); sy = fmaf(v1, y1, sy);
        qx = fmaf(v1 * x1, x1, qx); qy = fmaf(v1 * y1, y1, qy);
        sx = fmaf(v2, x2, sx); sy = fmaf(v2, y2, sy);
        qx = fmaf(v2 * x2, x2, qx); qy = fmaf(v2 * y2, y2, qy);
        sx = fmaf(v3, x3, sx); sy = fmaf(v3, y3, sy);
        qx = fmaf(v3 * x3, x3, qx); qy = fmaf(v3 * y3, y3, qy);
    }
    for (; e < end; ++e) {
        int2 c0 = ldnt(&pk[e]);
        uint u0 = Xb[(c0.x << 6) + lane];
        float v0 = __int_as_float(c0.y);
        float x0 = bfl(u0), y0 = bfh(u0);
        sx = fmaf(v0, x0, sx); sy = fmaf(v0, y0, sy);
        qx = fmaf(v0 * x0, x0, qx); qy = fmaf(v0 * y0, y0, qy);
    }
}

__global__ __launch_bounds__(256) void spmm_bp2(const int* __restrict__ rpA,
        const int2* __restrict__ pkA, const int* __restrict__ rpB,
        const int2* __restrict__ pkB, const uint* __restrict__ Xb,
        uint* __restrict__ outb, int N) {
    int w = threadIdx.x >> 6, lane = threadIdx.x & 63;
    int stride = gridDim.x * 4;
    for (int row = blockIdx.x * 4 + w; row < N; row += stride) {
        float sax = 0.f, say = 0.f, qax = 0.f, qay = 0.f;
        float sbx = 0.f, sby = 0.f, qbx = 0.f, qby = 0.f;
        row_gather_bp(pkA, rpA[row], rpA[row + 1], Xb, lane, sax, say, qax, qay);
        row_gather_bp(pkB, rpB[row], rpB[row + 1], Xb, lane, sbx, sby, qbx, qby);
        float tx = 0.5f * ((sax * sax - qax) - (sbx * sbx - qbx));
        float ty = 0.5f * ((say * say - qay) - (sby * sby - qby));
        outb[((size_t)row << 6) + lane] = packbf2(tx, ty);
    }
}

__global__ __launch_bounds__(256) void spmm_out(const int* __restrict__ rp0,
        const int2* __restrict__ pk0, const int* __restrict__ rp5,
        const int2* __restrict__ pk5, const int* __restrict__ rp6,
        const int2* __restrict__ pk6, const uint* __restrict__ Pb,
        const uint* __restrict__ t1b, const uint* __restrict__ t2b,
        float* __restrict__ out, int N) {
    int w = threadIdx.x >> 6, lane = threadIdx.x & 63;
    int stride = gridDim.x * 4;
    for (int row = blockIdx.x * 4 + w; row < N; row += stride) {
        float a0x = 0.f, a0y = 0.f, a5x = 0.f, a5y = 0.f, a6x = 0.f, a6y = 0.f;
        row_gather_sum(pk0, rp0[row], rp0[row + 1], Pb,  lane, a0x, a0y);
        row_gather_sum(pk5, rp5[row], rp5[row + 1], t1b, lane, a5x, a5y);
        row_gather_sum(pk6, rp6[row], rp6[row + 1], t2b, lane, a6x, a6y);
        float rx = fmaxf(0.5f * a0x + 0.25f * a5x + 0.25f * a6x, 0.f);
        float ry = fmaxf(0.5f * a0y + 0.25f * a5y + 0.25f * a6y, 0.f);
        *(float2*)(out + ((size_t)row << 7) + (lane << 1)) = make_float2(rx, ry);
    }
}

// ---------------- launch ----------------

extern "C" void kernel_launch(void* const* d_in, const int* in_sizes, int n_in,
                              void* d_out, int out_size, void* d_ws, size_t ws_size,
                              hipStream_t stream) {
    (void)n_in; (void)out_size; (void)ws_size;
    const float* x   = (const float*)d_in[0];
    const float* Wa  = (const float*)d_in[1];
    const float* Wb  = (const float*)d_in[2];
    const float* w1  = (const float*)d_in[4];
    const float* b1  = (const float*)d_in[5];
    const float* w2  = (const float*)d_in[6];
    const int* rows  = (const int*)d_in[7];
    const int* cols  = (const int*)d_in[8];
    const float* vals = (const float*)d_in[9];
    float* out = (float*)d_out;

    const int N = in_sizes[0] / 256;
    const int E = in_sizes[7] / 7;
    const int NSB = (N + SBROWS - 1) >> SBSHIFT;
    const int nchunks = (E + CH - 1) / CH;

    uint* Pb  = (uint*)d_ws;
    uint* t1b = Pb + (size_t)N * 64;
    uint* t2b = t1b + (size_t)N * 64;
    int2* pk  = (int2*)(t2b + (size_t)N * 64);
    size_t regionFloats = (size_t)N * 256;
    if ((size_t)8 * E > regionFloats) regionFloats = (size_t)8 * E;
    int2* stage = pk + (size_t)4 * E;
    float* AB   = (float*)stage;
    int* rp     = (int*)((float*)stage + regionFloats);
    int* offTab = rp + 4 * (size_t)(N + 1);
    int* lenTab = offTab + (size_t)4 * NSB * nchunks;
    int* bbase  = lenTab + (size_t)4 * NSB * nchunks;

    dim3 b256(256);
    int sgrid = (N + 3) / 4;
    int pgrid = PGRID; if (pgrid > sgrid) pgrid = sgrid;

    gemm_kernel<<<(N + BM - 1) / BM, b256, 0, stream>>>(x, Wa, Wb, AB, N);
    attn_kernel<<<sgrid, b256, 0, stream>>>(AB, w1, b1, w2, Pb, N);

    auto build = [&](int4 map, int nsup) {
        fill_chunk<<<dim3(nchunks, nsup), b256, 0, stream>>>(rows, cols, vals, map,
                                                             stage, offTab, lenTab, NSB, nchunks, E);
        bucket_scan<<<nsup, b256, 0, stream>>>(lenTab, bbase, NSB, nchunks);
        fill_bucket<<<dim3(NSB, nsup), dim3(1024), 0, stream>>>(stage, offTab, lenTab, bbase,
                                                                rp, pk, NSB, nchunks, N, E);
    };

    const int NP1 = N + 1;

    // group A: slots {1,3,2,4}
    build(make_int4(1, 3, 2, 4), 4);
    spmm_bp2<<<pgrid, b256, 0, stream>>>(rp + 0 * NP1, pk + 0 * (size_t)E,
                                         rp + 1 * NP1, pk + 1 * (size_t)E, Pb, t1b, N);
    spmm_bp2<<<pgrid, b256, 0, stream>>>(rp + 2 * NP1, pk + 2 * (size_t)E,
                                         rp + 3 * NP1, pk + 3 * (size_t)E, Pb, t2b, N);

    // group B: slots {0,5,6}
    build(make_int4(0, 5, 6, 6), 3);
    spmm_out<<<pgrid, b256, 0, stream>>>(rp + 0 * NP1, pk + 0 * (size_t)E,
                                         rp + 1 * NP1, pk + 1 * (size_t)E,
                                         rp + 2 * NP1, pk + 2 * (size_t)E,
                                         Pb, t1b, t2b, out, N);
}